// Round 16
// baseline (579.546 us; speedup 1.0000x reference)
//
#include <hip/hip_runtime.h>
#include <math.h>

#define B_ 32
#define L_ 256
#define C_ 55
#define D_ 512
#define H_ 8
#define NL_ 3
#define DF_ 512
#define Z_ 16
#define DK_ 64

typedef unsigned short u16;
typedef __attribute__((ext_vector_type(8))) short s16x8;
typedef __attribute__((ext_vector_type(8))) _Float16 f16x8;
typedef __attribute__((ext_vector_type(4))) float f32x4;

__device__ __forceinline__ u16 f2h(float f) {
  _Float16 h = (_Float16)f;
  return __builtin_bit_cast(u16, h);
}
__device__ __forceinline__ void gload16(const void* g, void* l) {
  __builtin_amdgcn_global_load_lds(
      (const __attribute__((address_space(1))) unsigned*)g,
      (__attribute__((address_space(3))) unsigned*)l, 16, 0, 0);
}

// ================= fp16 MFMA GEMM body: C = act(A @ B^T + bias) ============
// BK=64, chunk-XOR swizzled LDS. A: (M,K) fp16; B: (N,K) fp16. K % 64 == 0.
// MF: 16-row fragments per wave (wave tile = MF*16 x 64). BM = WM*MF*16.
// OUT: 0 fp32, 1 fp16. ACT: 0 none, 1 exact gelu. Cols >= nmax dropped.
template <int MF, int WM, int WN, int ACT, int OUT>
__device__ __forceinline__ void mgemm_body(
    char* As, char* Bs, const u16* __restrict__ A16,
    const u16* __restrict__ B16, const float* __restrict__ bias,
    float* __restrict__ Cf, u16* __restrict__ C16, int K, int lda, int ldb,
    int ldc, int nmax, int bxi, int byi) {
  constexpr int BM = WM * MF * 16, BN = WN * 64, T = WM * WN * 64;
  constexpr int ACH = BM * 8, BCH = BN * 8;  // 16B chunks per K-tile
  const int t = threadIdx.x, lane = t & 63, w = t >> 6;
  const int wm = w / WN, wn = w % WN;
  const long m0 = (long)byi * BM, n0 = (long)bxi * BN;
  const char* Ab = (const char*)(A16 + m0 * lda);
  const char* Bb = (const char*)(B16 + n0 * ldb);
  const int fr = lane & 15, gq = lane >> 4;
  const long lda2 = (long)lda * 2, ldb2 = (long)ldb * 2;
  f32x4 acc[MF][4] = {};
  for (int k0 = 0; k0 < K; k0 += 64) {
    const long kb = (long)k0 * 2;
#pragma unroll
    for (int e = 0; e < ACH; e += T) {
      int id = e + t;
      int row = id >> 3, c = (id & 7) ^ (row & 7);
      gload16(Ab + (long)row * lda2 + kb + c * 16, As + id * 16);
    }
#pragma unroll
    for (int e = 0; e < BCH; e += T) {
      int id = e + t;
      int row = id >> 3, c = (id & 7) ^ (row & 7);
      gload16(Bb + (long)row * ldb2 + kb + c * 16, Bs + id * 16);
    }
    __syncthreads();
#pragma unroll
    for (int ks = 0; ks < 2; ++ks) {
      f16x8 a[MF], b[4];
#pragma unroll
      for (int m = 0; m < MF; ++m) {
        int row = wm * (MF * 16) + m * 16 + fr;
        a[m] = *(const f16x8*)(As + row * 128 +
                               ((gq * 16 + ks * 64) ^ ((row & 7) << 4)));
      }
#pragma unroll
      for (int n = 0; n < 4; ++n) {
        int row = wn * 64 + n * 16 + fr;
        b[n] = *(const f16x8*)(Bs + row * 128 +
                               ((gq * 16 + ks * 64) ^ ((row & 7) << 4)));
      }
#pragma unroll
      for (int m = 0; m < MF; ++m)
#pragma unroll
        for (int n = 0; n < 4; ++n)
          acc[m][n] =
              __builtin_amdgcn_mfma_f32_16x16x32_f16(a[m], b[n], acc[m][n], 0, 0, 0);
    }
    __syncthreads();
  }
#pragma unroll
  for (int m = 0; m < MF; ++m) {
    long mg = m0 + wm * (MF * 16) + m * 16 + gq * 4;
#pragma unroll
    for (int n = 0; n < 4; ++n) {
      int ng = (int)n0 + wn * 64 + n * 16 + fr;
      if (ng >= nmax) continue;
      float bv = bias ? bias[ng] : 0.f;
#pragma unroll
      for (int r = 0; r < 4; ++r) {
        float v = acc[m][n][r] + bv;
        if (ACT == 1) v = 0.5f * v * (1.f + erff(v * 0.70710678118654752f));
        long idx = (mg + r) * ldc + ng;
        if (OUT == 0) Cf[idx] = v;
        if (OUT == 1) C16[idx] = f2h(v);
      }
    }
  }
}

template <int MF, int WM, int WN, int ACT, int OUT>
__global__ __launch_bounds__(WM * WN * 64) void mgemm(
    const u16* __restrict__ A16, const u16* __restrict__ B16,
    const float* __restrict__ bias, float* __restrict__ Cf,
    u16* __restrict__ C16, int K, int lda, int ldb, int ldc, int nmax) {
  __shared__ __align__(16) char As[WM * MF * 16 * 128];
  __shared__ __align__(16) char Bs[WN * 64 * 128];
  mgemm_body<MF, WM, WN, ACT, OUT>(As, Bs, A16, B16, bias, Cf, C16, K, lda,
                                   ldb, ldc, nmax, blockIdx.x, blockIdx.y);
}

// -- merged: sigma (8192, first) + q,k proj (2048, MF=1) + v^T (1024, MF=1) -
__global__ __launch_bounds__(256) void qkv_kernel(
    const u16* __restrict__ h16, const u16* __restrict__ w16,
    const float* __restrict__ bias, u16* __restrict__ qk16,
    u16* __restrict__ vt16, const float* __restrict__ h32,
    const float* __restrict__ sw, const float* __restrict__ sb,
    float* __restrict__ coef, float* __restrict__ c2f) {
  __shared__ __align__(16) char As[32 * 128];    // 4KB (MF=1)
  __shared__ __align__(16) char Bs[128 * 128];   // 16KB
  __shared__ float sm[4][8];
  int bx = blockIdx.x;
  if (bx < 8192) {
    // sigma body (identical to proven standalone sigma_kernel)
    int bl = bx;
    int l = bl & 255, b = bl >> 8;
    int t = threadIdx.x;
    const float* hrow = h32 + (long)bl * 512;
    float h0 = hrow[t], h1 = hrow[t + 256];
    float part[8];
#pragma unroll
    for (int hd = 0; hd < 8; ++hd) {
      const float* wrow = sw + hd * 512;
      part[hd] = h0 * wrow[t] + h1 * wrow[t + 256];
    }
#pragma unroll
    for (int off = 32; off > 0; off >>= 1)
#pragma unroll
      for (int hd = 0; hd < 8; ++hd) part[hd] += __shfl_xor(part[hd], off, 64);
    int wid = t >> 6;
    if ((t & 63) == 0) {
#pragma unroll
      for (int hd = 0; hd < 8; ++hd) sm[wid][hd] = part[hd];
    }
    __syncthreads();
    if (t < 8) {
      float sig = sm[0][t] + sm[1][t] + sm[2][t] + sm[3][t] + sb[t];
      sig = 1.f / (1.f + expf(-5.f * sig));
      sig += 1e-5f;
      sig = expf(sig * 1.0986122886681098f) - 1.f;
      long idx = ((long)(b * 8 + t) << 8) | l;
      coef[idx] = 0.3989422804014327f / sig;
      c2f[idx] = -0.5f / (sig * sig);
    }
  } else if (bx < 10240) {
    int b2 = bx - 8192;  // 2048 blocks: qk proj (8192 x 1024), BM=32 BN=128
    mgemm_body<1, 2, 2, 0, 1>(As, Bs, h16, w16, bias, nullptr, qk16, 512, 512,
                              512, 1024, 1024, b2 & 7, b2 >> 3);
  } else {
    int b3 = bx - 10240;  // 1024 blocks: vt (512 x 8192), BM=32 BN=128
    mgemm_body<1, 2, 2, 0, 1>(As, Bs, w16 + 1024 * 512, h16, nullptr, nullptr,
                              vt16, 512, 512, 512, 8192, 8192, b3 & 63,
                              b3 >> 6);
  }
}

// =============== fused attention: scores+softmax+series+prior+PV ===========
__global__ __launch_bounds__(256, 2) void fused_attn(
    const u16* __restrict__ qk16, const u16* __restrict__ vt16,
    const float* __restrict__ vbias, const float* __restrict__ coef,
    const float* __restrict__ c2f, float* __restrict__ ser,
    float* __restrict__ pri, u16* __restrict__ pv16) {
  __shared__ __align__(16) char smem[67584];
  char* Kreg = smem;                       // 32KB: K staging / P matrix (fp16)
  char* V0 = smem + 32768;                 // 16KB: Q stage then V half0
  char* V1 = smem + 49152;                 // 16KB: V half1
  float* rowred = (float*)(smem + 65536);  // 2048B = [4][64][2] floats
  const int t = threadIdx.x, lane = t & 63, w = t >> 6;
  const int fr = lane & 15, gq = lane >> 4;
  const int r0 = blockIdx.x * 64;
  const int bh = blockIdx.y, b = bh >> 3, h = bh & 7;
  const long qrow0 = (long)b * 256 + r0;
  const long krow0 = (long)b * 256;
  {
    const char* qs = (const char*)qk16 + qrow0 * 2048 + h * 128;
#pragma unroll
    for (int j = 0; j < 2; ++j) {
      int id = t + j * 256;
      int row = id >> 3, c = id & 7;
      *(s16x8*)(V0 + row * 144 + c * 16) =
          *(const s16x8*)(qs + (long)row * 2048 + c * 16);
    }
  }
  const char* kb = (const char*)qk16 + krow0 * 2048 + 1024 + h * 128;
#pragma unroll
  for (int j = 0; j < 8; ++j) {
    int id = t + j * 256;
    int row = id >> 3, c = (id & 7) ^ (row & 7);
    gload16(kb + (long)row * 2048 + c * 16, Kreg + id * 16);
  }
  __syncthreads();
  f32x4 acc[4][4] = {};
#pragma unroll
  for (int ks = 0; ks < 2; ++ks) {
    f16x8 aq[4], bk[4];
#pragma unroll
    for (int m = 0; m < 4; ++m)
      aq[m] = *(const f16x8*)(V0 + (m * 16 + fr) * 144 + gq * 16 + ks * 64);
#pragma unroll
    for (int n = 0; n < 4; ++n) {
      int row = w * 64 + n * 16 + fr;
      bk[n] = *(const f16x8*)(Kreg + row * 128 +
                              ((gq * 16 + ks * 64) ^ ((row & 7) << 4)));
    }
#pragma unroll
    for (int m = 0; m < 4; ++m)
#pragma unroll
      for (int n = 0; n < 4; ++n)
        acc[m][n] =
            __builtin_amdgcn_mfma_f32_16x16x32_f16(aq[m], bk[n], acc[m][n], 0, 0, 0);
  }
#pragma unroll
  for (int m = 0; m < 4; ++m)
#pragma unroll
    for (int n = 0; n < 4; ++n) acc[m][n] *= 0.125f;
  float lmax[4][4], lsum[4][4];
#pragma unroll
  for (int m = 0; m < 4; ++m)
#pragma unroll
    for (int r = 0; r < 4; ++r) {
      float v = fmaxf(fmaxf(acc[m][0][r], acc[m][1][r]),
                      fmaxf(acc[m][2][r], acc[m][3][r]));
#pragma unroll
      for (int off = 8; off > 0; off >>= 1) v = fmaxf(v, __shfl_xor(v, off, 64));
      lmax[m][r] = v;
    }
#pragma unroll
  for (int m = 0; m < 4; ++m)
#pragma unroll
    for (int n = 0; n < 4; ++n)
#pragma unroll
      for (int r = 0; r < 4; ++r)
        acc[m][n][r] = __expf(acc[m][n][r] - lmax[m][r]);
#pragma unroll
  for (int m = 0; m < 4; ++m)
#pragma unroll
    for (int r = 0; r < 4; ++r) {
      float s = acc[m][0][r] + acc[m][1][r] + acc[m][2][r] + acc[m][3][r];
#pragma unroll
      for (int off = 8; off > 0; off >>= 1) s += __shfl_xor(s, off, 64);
      lsum[m][r] = s;
    }
  if (fr == 0) {
#pragma unroll
    for (int m = 0; m < 4; ++m)
#pragma unroll
      for (int r = 0; r < 4; ++r) {
        int row = m * 16 + gq * 4 + r;
        rowred[(w * 64 + row) * 2] = lmax[m][r];
        rowred[(w * 64 + row) * 2 + 1] = lsum[m][r];
      }
  }
  __syncthreads();
  float scale[4][4];
#pragma unroll
  for (int m = 0; m < 4; ++m)
#pragma unroll
    for (int r = 0; r < 4; ++r) {
      int row = m * 16 + gq * 4 + r;
      float g = -1e30f, tot = 0.f;
      float2 pr[4];
#pragma unroll
      for (int ww = 0; ww < 4; ++ww) {
        pr[ww] = *(const float2*)&rowred[(ww * 64 + row) * 2];
        g = fmaxf(g, pr[ww].x);
      }
#pragma unroll
      for (int ww = 0; ww < 4; ++ww) tot += pr[ww].y * __expf(pr[ww].x - g);
      scale[m][r] = __expf(lmax[m][r] - g) / tot;
    }
  const char* vtb = (const char*)vt16 + ((long)h * 64 * 8192 + krow0) * 2;
#pragma unroll
  for (int j = 0; j < 4; ++j) {
    int id = t + j * 256;
    int row = id >> 5, c = (id & 31) ^ (row & 7);
    gload16(vtb + (long)row * 16384 + c * 16, V0 + id * 16);
    gload16(vtb + (long)(32 + row) * 16384 + c * 16, V1 + id * 16);
  }
  float* serb = ser + ((long)bh * 256 + r0) * 256 + w * 64;
  float* prib = pri + ((long)bh * 256 + r0) * 256 + w * 64;
  const float* cfb = coef + bh * 256 + r0;
  const float* ccb = c2f + bh * 256 + r0;
#pragma unroll
  for (int m = 0; m < 4; ++m)
#pragma unroll
    for (int r = 0; r < 4; ++r) {
      int row = m * 16 + gq * 4 + r;
      float cf = cfb[row], cc = ccb[row];
      float fl = (float)(r0 + row);
#pragma unroll
      for (int n = 0; n < 4; ++n) {
        int col = n * 16 + fr;
        float p = acc[m][n][r] * scale[m][r];
        serb[(long)row * 256 + col] = p;
        int pb = row * 512 + (((w * 64 + col) * 2) ^ ((row & 7) << 4));
        *(u16*)(Kreg + pb) = f2h(p);
        float dd = fl - (float)(w * 64 + col);
        prib[(long)row * 256 + col] = cf * __expf(cc * dd * dd);
      }
    }
  __syncthreads();  // drains both V halves + P visible
  f32x4 acc2[2][2] = {};
#pragma unroll
  for (int ks = 0; ks < 8; ++ks) {
    int arow = w * 16 + fr;
    f16x8 pa = *(const f16x8*)(
        Kreg + arow * 512 + ((gq * 16 + ks * 64) ^ ((arow & 7) << 4)));
#pragma unroll
    for (int n = 0; n < 2; ++n) {
      int vrow = n * 16 + fr;
      int vo = vrow * 512 + ((gq * 16 + ks * 64) ^ ((vrow & 7) << 4));
      f16x8 vb0 = *(const f16x8*)(V0 + vo);
      f16x8 vb1 = *(const f16x8*)(V1 + vo);
      acc2[0][n] = __builtin_amdgcn_mfma_f32_16x16x32_f16(pa, vb0, acc2[0][n], 0, 0, 0);
      acc2[1][n] = __builtin_amdgcn_mfma_f32_16x16x32_f16(pa, vb1, acc2[1][n], 0, 0, 0);
    }
  }
#pragma unroll
  for (int half = 0; half < 2; ++half)
#pragma unroll
    for (int n = 0; n < 2; ++n)
#pragma unroll
      for (int r = 0; r < 4; ++r) {
        int gcol = h * 64 + half * 32 + n * 16 + fr;
        long gm = qrow0 + w * 16 + gq * 4 + r;
        pv16[gm * 512 + gcol] = f2h(acc2[half][n][r] + vbias[gcol]);
      }
}

// ---------------- fp32 tiled GEMM (d1 only: K=16) --------------------------
template <int ACT, bool O16>
__global__ __launch_bounds__(256) void gemm_kernel(
    const float* __restrict__ A, const float* __restrict__ Bm,
    const float* __restrict__ bias, float* __restrict__ C,
    u16* __restrict__ C16, int M, int N, int K, int lda, int ldb, int ldc) {
  __shared__ float Asm[16][65];
  __shared__ float Bsm[16][65];
  int t = threadIdx.x;
  int tx = t & 15, ty = t >> 4;
  int n0 = blockIdx.x * 64, m0 = blockIdx.y * 64;
  float acc[4][4] = {};
  for (int k0 = 0; k0 < K; k0 += 16) {
#pragma unroll
    for (int e = 0; e < 4; ++e) {
      int idx = t + e * 256;
      int mi = idx >> 4, ki = idx & 15;
      int m = m0 + mi, kk = k0 + ki;
      Asm[ki][mi] = (m < M && kk < K) ? A[(long)m * lda + kk] : 0.f;
      int n = n0 + mi;
      Bsm[ki][mi] = (n < N && kk < K) ? Bm[(long)n * ldb + kk] : 0.f;
    }
    __syncthreads();
#pragma unroll
    for (int kk = 0; kk < 16; ++kk) {
      float a[4], b[4];
#pragma unroll
      for (int i = 0; i < 4; ++i) a[i] = Asm[kk][ty + 16 * i];
#pragma unroll
      for (int j = 0; j < 4; ++j) b[j] = Bsm[kk][tx + 16 * j];
#pragma unroll
      for (int i = 0; i < 4; ++i)
#pragma unroll
        for (int j = 0; j < 4; ++j) acc[i][j] = fmaf(a[i], b[j], acc[i][j]);
    }
    __syncthreads();
  }
#pragma unroll
  for (int i = 0; i < 4; ++i) {
    int m = m0 + ty + 16 * i;
    if (m >= M) continue;
#pragma unroll
    for (int j = 0; j < 4; ++j) {
      int n = n0 + tx + 16 * j;
      if (n >= N) continue;
      float v = acc[i][j];
      if (bias) v += bias[n];
      if (ACT == 2) v = fmaxf(v, 0.f);
      if (O16)
        C16[(long)m * ldc + n] = f2h(v);
      else
        C[(long)m * ldc + n] = v;
    }
  }
}

// -------- merged one-time prep: embed (512 blocks) + all weight convs ------
__global__ __launch_bounds__(256) void conv_embed_kernel(
    const float* __restrict__ x, const float* __restrict__ tw,
    const float* __restrict__ qkv_w, const float* __restrict__ out_w,
    const float* __restrict__ c1w, const float* __restrict__ c2w,
    const float* __restrict__ latw, const float* __restrict__ d2w,
    float* __restrict__ h32, u16* __restrict__ h16, u16* __restrict__ wqkv16,
    u16* __restrict__ wo16, u16* __restrict__ c116, u16* __restrict__ c216,
    u16* __restrict__ latpad, u16* __restrict__ d2pad) {
  __shared__ float xs[18][56];
  int bx = blockIdx.x;
  int t = threadIdx.x;
  if (bx < 512) {
    int lt = (bx & 15) * 16;
    int b = bx >> 4;
    for (int idx = t; idx < 18 * 55; idx += 256) {
      int rr = idx / 55, cc = idx % 55;
      int gl = (lt + rr - 1 + L_) & (L_ - 1);
      xs[rr][cc] = x[(long)(b * L_ + gl) * C_ + cc];
    }
    __syncthreads();
    for (int dp = 0; dp < 2; ++dp) {
      int d = t + dp * 256;
      float acc[16] = {};
      const float* wr = tw + (long)d * (C_ * 3);
      for (int c = 0; c < C_; ++c) {
#pragma unroll
        for (int w = 0; w < 3; ++w) {
          float wv = wr[c * 3 + w];
#pragma unroll
          for (int l = 0; l < 16; ++l) acc[l] = fmaf(xs[l + w][c], wv, acc[l]);
        }
      }
      float ang_scale = expf(-(float)(d & ~1) * 0.017988946039015984f);
#pragma unroll
      for (int l = 0; l < 16; ++l) {
        float ang = (float)(lt + l) * ang_scale;
        float pe = (d & 1) ? cosf(ang) : sinf(ang);
        float v = acc[l] + pe;
        long idx = (long)(b * L_ + lt + l) * D_ + d;
        h32[idx] = v;
        h16[idx] = f2h(v);
      }
    }
    return;
  }
  int cb = bx - 512;
  if (cb < 9216) {
    int i = cb * 256 + t;
    wqkv16[i] = f2h(qkv_w[i]);
  } else if (cb < 12288) {
    int i = (cb - 9216) * 256 + t;
    wo16[i] = f2h(out_w[i]);
  } else if (cb < 15360) {
    int i = (cb - 12288) * 256 + t;
    c116[i] = f2h(c1w[i]);
  } else if (cb < 18432) {
    int i = (cb - 15360) * 256 + t;
    c216[i] = f2h(c2w[i]);
  } else if (cb < 18560) {
    int i = (cb - 18432) * 256 + t;
    int r = i >> 9, c = i & 511;
    latpad[i] = (r < Z_) ? f2h(latw[r * 512 + c]) : (u16)0;
  } else {
    int i = (cb - 18560) * 256 + t;
    int r = i >> 9, c = i & 511;
    d2pad[i] = (r < C_) ? f2h(d2w[r * 512 + c]) : (u16)0;
  }
}

// --------- wave-per-row residual + LN (+ optional fused second LN) ---------
// 4 rows/block (one per wave), no block barriers. Row held in 8 regs/lane.
__global__ __launch_bounds__(256) void lnw_kernel(
    const float* __restrict__ a, const float* __restrict__ r,
    const float* __restrict__ gg, const float* __restrict__ be,
    float* __restrict__ ofp, u16* __restrict__ o16,
    const float* __restrict__ g2, const float* __restrict__ b2) {
  int wave = threadIdx.x >> 6, lane = threadIdx.x & 63;
  long row = (long)blockIdx.x * 4 + wave;
  long base = row * D_ + lane * 8;
  int cb = lane * 8;
  f32x4 xa = *(const f32x4*)(a + base);
  f32x4 xb = *(const f32x4*)(a + base + 4);
  if (r) {
    xa += *(const f32x4*)(r + base);
    xb += *(const f32x4*)(r + base + 4);
  }
  float x[8] = {xa.x, xa.y, xa.z, xa.w, xb.x, xb.y, xb.z, xb.w};
  float s = 0.f;
#pragma unroll
  for (int e = 0; e < 8; ++e) s += x[e];
#pragma unroll
  for (int off = 32; off > 0; off >>= 1) s += __shfl_xor(s, off, 64);
  float mean = s * (1.f / D_);
  float vv = 0.f;
#pragma unroll
  for (int e = 0; e < 8; ++e) {
    x[e] -= mean;
    vv += x[e] * x[e];
  }
#pragma unroll
  for (int off = 32; off > 0; off >>= 1) vv += __shfl_xor(vv, off, 64);
  float rstd = rsqrtf(vv * (1.f / D_) + 1e-5f);
  f32x4 ga = *(const f32x4*)(gg + cb), gb = *(const f32x4*)(gg + cb + 4);
  f32x4 ba = *(const f32x4*)(be + cb), bb = *(const f32x4*)(be + cb + 4);
  float g[8] = {ga.x, ga.y, ga.z, ga.w, gb.x, gb.y, gb.z, gb.w};
  float bi[8] = {ba.x, ba.y, ba.z, ba.w, bb.x, bb.y, bb.z, bb.w};
  float v[8];
#pragma unroll
  for (int e = 0; e < 8; ++e) v[e] = x[e] * rstd * g[e] + bi[e];
  if (ofp) {
    f32x4 oa = {v[0], v[1], v[2], v[3]}, ob = {v[4], v[5], v[6], v[7]};
    *(f32x4*)(ofp + base) = oa;
    *(f32x4*)(ofp + base + 4) = ob;
  }
  if (g2) {
    float s2 = 0.f;
#pragma unroll
    for (int e = 0; e < 8; ++e) s2 += v[e];
#pragma unroll
    for (int off = 32; off > 0; off >>= 1) s2 += __shfl_xor(s2, off, 64);
    float mean2 = s2 * (1.f / D_);
    float vv2 = 0.f;
#pragma unroll
    for (int e = 0; e < 8; ++e) {
      v[e] -= mean2;
      vv2 += v[e] * v[e];
    }
#pragma unroll
    for (int off = 32; off > 0; off >>= 1) vv2 += __shfl_xor(vv2, off, 64);
    float rstd2 = rsqrtf(vv2 * (1.f / D_) + 1e-5f);
    f32x4 g2a = *(const f32x4*)(g2 + cb), g2b = *(const f32x4*)(g2 + cb + 4);
    f32x4 b2a = *(const f32x4*)(b2 + cb), b2b = *(const f32x4*)(b2 + cb + 4);
    float gg2[8] = {g2a.x, g2a.y, g2a.z, g2a.w, g2b.x, g2b.y, g2b.z, g2b.w};
    float bb2[8] = {b2a.x, b2a.y, b2a.z, b2a.w, b2b.x, b2b.y, b2b.z, b2b.w};
#pragma unroll
    for (int e = 0; e < 8; ++e) v[e] = v[e] * rstd2 * gg2[e] + bb2[e];
  }
  if (o16) {
    u16 h[8];
#pragma unroll
    for (int e = 0; e < 8; ++e) h[e] = f2h(v[e]);
    *(s16x8*)(o16 + base) = *(s16x8*)h;
  }
}

extern "C" void kernel_launch(void* const* d_in, const int* in_sizes, int n_in,
                              void* d_out, int out_size, void* d_ws,
                              size_t ws_size, hipStream_t stream) {
  (void)in_sizes; (void)n_in; (void)out_size; (void)ws_size;
  const float* x = (const float*)d_in[0];
  const float* tok_w = (const float*)d_in[1];
  const float* qkv_w = (const float*)d_in[2];
  const float* qkv_b = (const float*)d_in[3];
  const float* sig_w = (const float*)d_in[4];
  const float* sig_b = (const float*)d_in[5];
  const float* out_w = (const float*)d_in[6];
  const float* out_b = (const float*)d_in[7];
  const float* c1w = (const float*)d_in[8];
  const float* c1b = (const float*)d_in[9];
  const float* c2w = (const float*)d_in[10];
  const float* c2b = (const float*)d_in[11];
  const float* ln1g = (const float*)d_in[12];
  const float* ln1b = (const float*)d_in[13];
  const float* ln2g = (const float*)d_in[14];
  const float* ln2b = (const float*)d_in[15];
  const float* lnfg = (const float*)d_in[16];
  const float* lnfb = (const float*)d_in[17];
  const float* latw = (const float*)d_in[18];
  const float* latb = (const float*)d_in[19];
  const float* d1w = (const float*)d_in[20];
  const float* d1b = (const float*)d_in[21];
  const float* d2w = (const float*)d_in[22];
  const float* d2b = (const float*)d_in[23];
  float* out = (float*)d_out;

  const long BLD = (long)B_ * L_ * D_;         // 4194304
  const long CHUNK = (long)B_ * H_ * L_ * L_;  // 16777216
  const long SER_OFF = (long)B_ * L_ * C_;
  const long PRI_OFF = SER_OFF + NL_ * CHUNK;
  const long Z_OFF = PRI_OFF + NL_ * CHUNK;
  const int M = B_ * L_;  // 8192
  const int DD = D_ * D_;

  char* wp = (char*)d_ws;
  auto alloc = [&](size_t bytes) {
    char* p = wp;
    wp += (bytes + 255) & ~(size_t)255;
    return p;
  };
  float* h32 = (float*)alloc(BLD * 4);
  u16* h16 = (u16*)alloc(BLD * 2);
  float* tb = (float*)alloc(BLD * 4);
  u16* qk16 = (u16*)alloc(BLD * 4);  // (M,1024); reused as y16
  u16* vt16 = (u16*)alloc(BLD * 2);  // also dec16 at tail
  u16* pv16 = (u16*)alloc(BLD * 2);
  float* coef = (float*)alloc((size_t)B_ * H_ * L_ * 4);
  float* c2f = (float*)alloc((size_t)B_ * H_ * L_ * 4);
  u16* wqkv16 = (u16*)alloc((size_t)NL_ * 3 * DD * 2);
  u16* wo16 = (u16*)alloc((size_t)NL_ * DD * 2);
  u16* c116 = (u16*)alloc((size_t)NL_ * DD * 2);
  u16* c216 = (u16*)alloc((size_t)NL_ * DD * 2);
  u16* latpad = (u16*)alloc((size_t)64 * 512 * 2);
  u16* d2pad = (u16*)alloc((size_t)64 * 512 * 2);

  // one-time prep: embed + all weight conversions, one launch (18688 blocks)
  conv_embed_kernel<<<18688, 256, 0, stream>>>(
      x, tok_w, qkv_w, out_w, c1w, c2w, latw, d2w, h32, h16, wqkv16, wo16,
      c116, c216, latpad, d2pad);

  for (int i = 0; i < NL_; ++i) {
    const long ofQK = (long)(i * 3) * DD;
    // merged sigma (first) + q,k projection (MF=1) + v^T (MF=1), 11264 blocks
    qkv_kernel<<<11264, 256, 0, stream>>>(
        h16, wqkv16 + ofQK, qkv_b + (long)i * 3 * D_, qk16, vt16, h32,
        sig_w + (long)i * H_ * D_, sig_b + i * H_, coef, c2f);
    fused_attn<<<dim3(4, 256), 256, 0, stream>>>(
        qk16, vt16, qkv_b + (long)(i * 3 + 2) * D_, coef, c2f,
        out + SER_OFF + i * CHUNK, out + PRI_OFF + i * CHUNK, pv16);
    // out projection (fp32 out), MF=1: 4096 waves (4/SIMD)
    mgemm<1, 2, 1, 0, 0><<<dim3(8, 256), 128, 0, stream>>>(
        pv16, wo16 + (long)i * DD, out_b + i * D_, tb, nullptr, D_, D_, D_, D_,
        D_);
    lnw_kernel<<<M / 4, 256, 0, stream>>>(h32, tb, ln1g + i * D_,
                                          ln1b + i * D_, h32, h16, nullptr,
                                          nullptr);
    // FFN (intermediate y16 reuses qk16), MF=1
    u16* y16 = qk16;
    mgemm<1, 2, 1, 1, 1><<<dim3(8, 256), 128, 0, stream>>>(
        h16, c116 + (long)i * DD, c1b + i * DF_, nullptr, y16, D_, D_, D_, DF_,
        DF_);
    mgemm<1, 2, 1, 0, 0><<<dim3(8, 256), 128, 0, stream>>>(
        y16, c216 + (long)i * DD, c2b + i * D_, tb, nullptr, DF_, DF_, DF_, D_,
        D_);
    // trailing LN; layer 2 fuses the final LN (h32 no longer needed then)
    bool last = (i == NL_ - 1);
    lnw_kernel<<<M / 4, 256, 0, stream>>>(
        h32, tb, ln2g + i * D_, ln2b + i * D_, last ? nullptr : h32, h16,
        last ? lnfg : nullptr, last ? lnfb : nullptr);
  }
  // latent: z = LNf(h) @ latw^T + latb  (fp16 MFMA, N=16 guarded), MF=2
  mgemm<2, 2, 1, 0, 0><<<dim3(1, 128), 128, 0, stream>>>(
      h16, latpad, latb, out + Z_OFF, nullptr, D_, D_, D_, Z_, Z_);
  // d1: relu(z @ d1w^T + d1b) -> fp16 (K=16, fp32 path)
  u16* dec16 = vt16;
  gemm_kernel<2, true><<<dim3(8, 128), 256, 0, stream>>>(
      out + Z_OFF, d1w, d1b, nullptr, dec16, M, D_, Z_, Z_, Z_, D_);
  // d2: recon = dec @ d2w^T + d2b (fp16 MFMA, N=55 guarded), MF=2
  mgemm<2, 2, 1, 0, 0><<<dim3(1, 128), 128, 0, stream>>>(
      dec16, d2pad, d2b, out, nullptr, D_, D_, D_, C_, C_);
}

// Round 17
// 570.926 us; speedup vs baseline: 1.0151x; 1.0151x over previous
//
#include <hip/hip_runtime.h>
#include <math.h>

#define B_ 32
#define L_ 256
#define C_ 55
#define D_ 512
#define H_ 8
#define NL_ 3
#define DF_ 512
#define Z_ 16
#define DK_ 64

typedef unsigned short u16;
typedef __attribute__((ext_vector_type(8))) short s16x8;
typedef __attribute__((ext_vector_type(8))) _Float16 f16x8;
typedef __attribute__((ext_vector_type(4))) float f32x4;

__device__ __forceinline__ u16 f2h(float f) {
  _Float16 h = (_Float16)f;
  return __builtin_bit_cast(u16, h);
}
__device__ __forceinline__ void gload16(const void* g, void* l) {
  __builtin_amdgcn_global_load_lds(
      (const __attribute__((address_space(1))) unsigned*)g,
      (__attribute__((address_space(3))) unsigned*)l, 16, 0, 0);
}

// ================= fp16 MFMA GEMM body: C = act(A @ B^T + bias) ============
// BK=64, chunk-XOR swizzled LDS. A: (M,K) fp16; B: (N,K) fp16. K % 64 == 0.
// MF: 16-row fragments per wave (wave tile = MF*16 x 64). BM = WM*MF*16.
// OUT: 0 fp32, 1 fp16. ACT: 0 none, 1 exact gelu. Cols >= nmax dropped.
template <int MF, int WM, int WN, int ACT, int OUT>
__device__ __forceinline__ void mgemm_body(
    char* As, char* Bs, const u16* __restrict__ A16,
    const u16* __restrict__ B16, const float* __restrict__ bias,
    float* __restrict__ Cf, u16* __restrict__ C16, int K, int lda, int ldb,
    int ldc, int nmax, int bxi, int byi) {
  constexpr int BM = WM * MF * 16, BN = WN * 64, T = WM * WN * 64;
  constexpr int ACH = BM * 8, BCH = BN * 8;  // 16B chunks per K-tile
  const int t = threadIdx.x, lane = t & 63, w = t >> 6;
  const int wm = w / WN, wn = w % WN;
  const long m0 = (long)byi * BM, n0 = (long)bxi * BN;
  const char* Ab = (const char*)(A16 + m0 * lda);
  const char* Bb = (const char*)(B16 + n0 * ldb);
  const int fr = lane & 15, gq = lane >> 4;
  const long lda2 = (long)lda * 2, ldb2 = (long)ldb * 2;
  f32x4 acc[MF][4] = {};
  for (int k0 = 0; k0 < K; k0 += 64) {
    const long kb = (long)k0 * 2;
#pragma unroll
    for (int e = 0; e < ACH; e += T) {
      int id = e + t;
      int row = id >> 3, c = (id & 7) ^ (row & 7);
      gload16(Ab + (long)row * lda2 + kb + c * 16, As + id * 16);
    }
#pragma unroll
    for (int e = 0; e < BCH; e += T) {
      int id = e + t;
      int row = id >> 3, c = (id & 7) ^ (row & 7);
      gload16(Bb + (long)row * ldb2 + kb + c * 16, Bs + id * 16);
    }
    __syncthreads();
#pragma unroll
    for (int ks = 0; ks < 2; ++ks) {
      f16x8 a[MF], b[4];
#pragma unroll
      for (int m = 0; m < MF; ++m) {
        int row = wm * (MF * 16) + m * 16 + fr;
        a[m] = *(const f16x8*)(As + row * 128 +
                               ((gq * 16 + ks * 64) ^ ((row & 7) << 4)));
      }
#pragma unroll
      for (int n = 0; n < 4; ++n) {
        int row = wn * 64 + n * 16 + fr;
        b[n] = *(const f16x8*)(Bs + row * 128 +
                               ((gq * 16 + ks * 64) ^ ((row & 7) << 4)));
      }
#pragma unroll
      for (int m = 0; m < MF; ++m)
#pragma unroll
        for (int n = 0; n < 4; ++n)
          acc[m][n] =
              __builtin_amdgcn_mfma_f32_16x16x32_f16(a[m], b[n], acc[m][n], 0, 0, 0);
    }
    __syncthreads();
  }
#pragma unroll
  for (int m = 0; m < MF; ++m) {
    long mg = m0 + wm * (MF * 16) + m * 16 + gq * 4;
#pragma unroll
    for (int n = 0; n < 4; ++n) {
      int ng = (int)n0 + wn * 64 + n * 16 + fr;
      if (ng >= nmax) continue;
      float bv = bias ? bias[ng] : 0.f;
#pragma unroll
      for (int r = 0; r < 4; ++r) {
        float v = acc[m][n][r] + bv;
        if (ACT == 1) v = 0.5f * v * (1.f + erff(v * 0.70710678118654752f));
        long idx = (mg + r) * ldc + ng;
        if (OUT == 0) Cf[idx] = v;
        if (OUT == 1) C16[idx] = f2h(v);
      }
    }
  }
}

template <int MF, int WM, int WN, int ACT, int OUT>
__global__ __launch_bounds__(WM * WN * 64) void mgemm(
    const u16* __restrict__ A16, const u16* __restrict__ B16,
    const float* __restrict__ bias, float* __restrict__ Cf,
    u16* __restrict__ C16, int K, int lda, int ldb, int ldc, int nmax) {
  __shared__ __align__(16) char As[WM * MF * 16 * 128];
  __shared__ __align__(16) char Bs[WN * 64 * 128];
  mgemm_body<MF, WM, WN, ACT, OUT>(As, Bs, A16, B16, bias, Cf, C16, K, lda,
                                   ldb, ldc, nmax, blockIdx.x, blockIdx.y);
}

// -- merged: sigma (8192, first) + q,k proj (1024, MF=2) + v^T (512) -------
__global__ __launch_bounds__(256) void qkv_kernel(
    const u16* __restrict__ h16, const u16* __restrict__ w16,
    const float* __restrict__ bias, u16* __restrict__ qk16,
    u16* __restrict__ vt16, const float* __restrict__ h32,
    const float* __restrict__ sw, const float* __restrict__ sb,
    float* __restrict__ coef, float* __restrict__ c2f) {
  __shared__ __align__(16) char As[128 * 128];
  __shared__ __align__(16) char Bs[128 * 128];
  __shared__ float sm[4][8];
  int bx = blockIdx.x;
  if (bx < 8192) {
    // sigma body (identical to proven standalone sigma_kernel)
    int bl = bx;
    int l = bl & 255, b = bl >> 8;
    int t = threadIdx.x;
    const float* hrow = h32 + (long)bl * 512;
    float h0 = hrow[t], h1 = hrow[t + 256];
    float part[8];
#pragma unroll
    for (int hd = 0; hd < 8; ++hd) {
      const float* wrow = sw + hd * 512;
      part[hd] = h0 * wrow[t] + h1 * wrow[t + 256];
    }
#pragma unroll
    for (int off = 32; off > 0; off >>= 1)
#pragma unroll
      for (int hd = 0; hd < 8; ++hd) part[hd] += __shfl_xor(part[hd], off, 64);
    int wid = t >> 6;
    if ((t & 63) == 0) {
#pragma unroll
      for (int hd = 0; hd < 8; ++hd) sm[wid][hd] = part[hd];
    }
    __syncthreads();
    if (t < 8) {
      float sig = sm[0][t] + sm[1][t] + sm[2][t] + sm[3][t] + sb[t];
      sig = 1.f / (1.f + expf(-5.f * sig));
      sig += 1e-5f;
      sig = expf(sig * 1.0986122886681098f) - 1.f;
      long idx = ((long)(b * 8 + t) << 8) | l;
      coef[idx] = 0.3989422804014327f / sig;
      c2f[idx] = -0.5f / (sig * sig);
    }
  } else if (bx < 9216) {
    int b2 = bx - 8192;  // 1024 blocks: qk proj (8192 x 1024), BM=64 BN=128
    mgemm_body<2, 2, 2, 0, 1>(As, Bs, h16, w16, bias, nullptr, qk16, 512, 512,
                              512, 1024, 1024, b2 & 7, b2 >> 3);
  } else {
    int b3 = bx - 9216;  // 512 blocks: vt (512 x 8192), BM=64 BN=128
    mgemm_body<2, 2, 2, 0, 1>(As, Bs, w16 + 1024 * 512, h16, nullptr, nullptr,
                              vt16, 512, 512, 512, 8192, 8192, b3 & 63,
                              b3 >> 6);
  }
}

// =============== fused attention: scores+softmax+series+prior+PV ===========
__global__ __launch_bounds__(256, 2) void fused_attn(
    const u16* __restrict__ qk16, const u16* __restrict__ vt16,
    const float* __restrict__ vbias, const float* __restrict__ coef,
    const float* __restrict__ c2f, float* __restrict__ ser,
    float* __restrict__ pri, u16* __restrict__ pv16) {
  __shared__ __align__(16) char smem[67584];
  char* Kreg = smem;                       // 32KB: K staging / P matrix (fp16)
  char* V0 = smem + 32768;                 // 16KB: Q stage then V half0
  char* V1 = smem + 49152;                 // 16KB: V half1
  float* rowred = (float*)(smem + 65536);  // 2048B = [4][64][2] floats
  const int t = threadIdx.x, lane = t & 63, w = t >> 6;
  const int fr = lane & 15, gq = lane >> 4;
  const int r0 = blockIdx.x * 64;
  const int bh = blockIdx.y, b = bh >> 3, h = bh & 7;
  const long qrow0 = (long)b * 256 + r0;
  const long krow0 = (long)b * 256;
  {
    const char* qs = (const char*)qk16 + qrow0 * 2048 + h * 128;
#pragma unroll
    for (int j = 0; j < 2; ++j) {
      int id = t + j * 256;
      int row = id >> 3, c = id & 7;
      *(s16x8*)(V0 + row * 144 + c * 16) =
          *(const s16x8*)(qs + (long)row * 2048 + c * 16);
    }
  }
  const char* kb = (const char*)qk16 + krow0 * 2048 + 1024 + h * 128;
#pragma unroll
  for (int j = 0; j < 8; ++j) {
    int id = t + j * 256;
    int row = id >> 3, c = (id & 7) ^ (row & 7);
    gload16(kb + (long)row * 2048 + c * 16, Kreg + id * 16);
  }
  __syncthreads();
  f32x4 acc[4][4] = {};
#pragma unroll
  for (int ks = 0; ks < 2; ++ks) {
    f16x8 aq[4], bk[4];
#pragma unroll
    for (int m = 0; m < 4; ++m)
      aq[m] = *(const f16x8*)(V0 + (m * 16 + fr) * 144 + gq * 16 + ks * 64);
#pragma unroll
    for (int n = 0; n < 4; ++n) {
      int row = w * 64 + n * 16 + fr;
      bk[n] = *(const f16x8*)(Kreg + row * 128 +
                              ((gq * 16 + ks * 64) ^ ((row & 7) << 4)));
    }
#pragma unroll
    for (int m = 0; m < 4; ++m)
#pragma unroll
      for (int n = 0; n < 4; ++n)
        acc[m][n] =
            __builtin_amdgcn_mfma_f32_16x16x32_f16(aq[m], bk[n], acc[m][n], 0, 0, 0);
  }
#pragma unroll
  for (int m = 0; m < 4; ++m)
#pragma unroll
    for (int n = 0; n < 4; ++n) acc[m][n] *= 0.125f;
  float lmax[4][4], lsum[4][4];
#pragma unroll
  for (int m = 0; m < 4; ++m)
#pragma unroll
    for (int r = 0; r < 4; ++r) {
      float v = fmaxf(fmaxf(acc[m][0][r], acc[m][1][r]),
                      fmaxf(acc[m][2][r], acc[m][3][r]));
#pragma unroll
      for (int off = 8; off > 0; off >>= 1) v = fmaxf(v, __shfl_xor(v, off, 64));
      lmax[m][r] = v;
    }
#pragma unroll
  for (int m = 0; m < 4; ++m)
#pragma unroll
    for (int n = 0; n < 4; ++n)
#pragma unroll
      for (int r = 0; r < 4; ++r)
        acc[m][n][r] = __expf(acc[m][n][r] - lmax[m][r]);
#pragma unroll
  for (int m = 0; m < 4; ++m)
#pragma unroll
    for (int r = 0; r < 4; ++r) {
      float s = acc[m][0][r] + acc[m][1][r] + acc[m][2][r] + acc[m][3][r];
#pragma unroll
      for (int off = 8; off > 0; off >>= 1) s += __shfl_xor(s, off, 64);
      lsum[m][r] = s;
    }
  if (fr == 0) {
#pragma unroll
    for (int m = 0; m < 4; ++m)
#pragma unroll
      for (int r = 0; r < 4; ++r) {
        int row = m * 16 + gq * 4 + r;
        rowred[(w * 64 + row) * 2] = lmax[m][r];
        rowred[(w * 64 + row) * 2 + 1] = lsum[m][r];
      }
  }
  __syncthreads();
  float scale[4][4];
#pragma unroll
  for (int m = 0; m < 4; ++m)
#pragma unroll
    for (int r = 0; r < 4; ++r) {
      int row = m * 16 + gq * 4 + r;
      float g = -1e30f, tot = 0.f;
      float2 pr[4];
#pragma unroll
      for (int ww = 0; ww < 4; ++ww) {
        pr[ww] = *(const float2*)&rowred[(ww * 64 + row) * 2];
        g = fmaxf(g, pr[ww].x);
      }
#pragma unroll
      for (int ww = 0; ww < 4; ++ww) tot += pr[ww].y * __expf(pr[ww].x - g);
      scale[m][r] = __expf(lmax[m][r] - g) / tot;
    }
  const char* vtb = (const char*)vt16 + ((long)h * 64 * 8192 + krow0) * 2;
#pragma unroll
  for (int j = 0; j < 4; ++j) {
    int id = t + j * 256;
    int row = id >> 5, c = (id & 31) ^ (row & 7);
    gload16(vtb + (long)row * 16384 + c * 16, V0 + id * 16);
    gload16(vtb + (long)(32 + row) * 16384 + c * 16, V1 + id * 16);
  }
  float* serb = ser + ((long)bh * 256 + r0) * 256 + w * 64;
  float* prib = pri + ((long)bh * 256 + r0) * 256 + w * 64;
  const float* cfb = coef + bh * 256 + r0;
  const float* ccb = c2f + bh * 256 + r0;
#pragma unroll
  for (int m = 0; m < 4; ++m)
#pragma unroll
    for (int r = 0; r < 4; ++r) {
      int row = m * 16 + gq * 4 + r;
      float cf = cfb[row], cc = ccb[row];
      float fl = (float)(r0 + row);
#pragma unroll
      for (int n = 0; n < 4; ++n) {
        int col = n * 16 + fr;
        float p = acc[m][n][r] * scale[m][r];
        serb[(long)row * 256 + col] = p;
        int pb = row * 512 + (((w * 64 + col) * 2) ^ ((row & 7) << 4));
        *(u16*)(Kreg + pb) = f2h(p);
        float dd = fl - (float)(w * 64 + col);
        prib[(long)row * 256 + col] = cf * __expf(cc * dd * dd);
      }
    }
  __syncthreads();  // drains both V halves + P visible
  f32x4 acc2[2][2] = {};
#pragma unroll
  for (int ks = 0; ks < 8; ++ks) {
    int arow = w * 16 + fr;
    f16x8 pa = *(const f16x8*)(
        Kreg + arow * 512 + ((gq * 16 + ks * 64) ^ ((arow & 7) << 4)));
#pragma unroll
    for (int n = 0; n < 2; ++n) {
      int vrow = n * 16 + fr;
      int vo = vrow * 512 + ((gq * 16 + ks * 64) ^ ((vrow & 7) << 4));
      f16x8 vb0 = *(const f16x8*)(V0 + vo);
      f16x8 vb1 = *(const f16x8*)(V1 + vo);
      acc2[0][n] = __builtin_amdgcn_mfma_f32_16x16x32_f16(pa, vb0, acc2[0][n], 0, 0, 0);
      acc2[1][n] = __builtin_amdgcn_mfma_f32_16x16x32_f16(pa, vb1, acc2[1][n], 0, 0, 0);
    }
  }
#pragma unroll
  for (int half = 0; half < 2; ++half)
#pragma unroll
    for (int n = 0; n < 2; ++n)
#pragma unroll
      for (int r = 0; r < 4; ++r) {
        int gcol = h * 64 + half * 32 + n * 16 + fr;
        long gm = qrow0 + w * 16 + gq * 4 + r;
        pv16[gm * 512 + gcol] = f2h(acc2[half][n][r] + vbias[gcol]);
      }
}

// ---------------- fp32 tiled GEMM (d1 only: K=16) --------------------------
template <int ACT, bool O16>
__global__ __launch_bounds__(256) void gemm_kernel(
    const float* __restrict__ A, const float* __restrict__ Bm,
    const float* __restrict__ bias, float* __restrict__ C,
    u16* __restrict__ C16, int M, int N, int K, int lda, int ldb, int ldc) {
  __shared__ float Asm[16][65];
  __shared__ float Bsm[16][65];
  int t = threadIdx.x;
  int tx = t & 15, ty = t >> 4;
  int n0 = blockIdx.x * 64, m0 = blockIdx.y * 64;
  float acc[4][4] = {};
  for (int k0 = 0; k0 < K; k0 += 16) {
#pragma unroll
    for (int e = 0; e < 4; ++e) {
      int idx = t + e * 256;
      int mi = idx >> 4, ki = idx & 15;
      int m = m0 + mi, kk = k0 + ki;
      Asm[ki][mi] = (m < M && kk < K) ? A[(long)m * lda + kk] : 0.f;
      int n = n0 + mi;
      Bsm[ki][mi] = (n < N && kk < K) ? Bm[(long)n * ldb + kk] : 0.f;
    }
    __syncthreads();
#pragma unroll
    for (int kk = 0; kk < 16; ++kk) {
      float a[4], b[4];
#pragma unroll
      for (int i = 0; i < 4; ++i) a[i] = Asm[kk][ty + 16 * i];
#pragma unroll
      for (int j = 0; j < 4; ++j) b[j] = Bsm[kk][tx + 16 * j];
#pragma unroll
      for (int i = 0; i < 4; ++i)
#pragma unroll
        for (int j = 0; j < 4; ++j) acc[i][j] = fmaf(a[i], b[j], acc[i][j]);
    }
    __syncthreads();
  }
#pragma unroll
  for (int i = 0; i < 4; ++i) {
    int m = m0 + ty + 16 * i;
    if (m >= M) continue;
#pragma unroll
    for (int j = 0; j < 4; ++j) {
      int n = n0 + tx + 16 * j;
      if (n >= N) continue;
      float v = acc[i][j];
      if (bias) v += bias[n];
      if (ACT == 2) v = fmaxf(v, 0.f);
      if (O16)
        C16[(long)m * ldc + n] = f2h(v);
      else
        C[(long)m * ldc + n] = v;
    }
  }
}

// -------- merged one-time prep: embed (512 blocks) + all weight convs ------
__global__ __launch_bounds__(256) void conv_embed_kernel(
    const float* __restrict__ x, const float* __restrict__ tw,
    const float* __restrict__ qkv_w, const float* __restrict__ out_w,
    const float* __restrict__ c1w, const float* __restrict__ c2w,
    const float* __restrict__ latw, const float* __restrict__ d2w,
    float* __restrict__ h32, u16* __restrict__ h16, u16* __restrict__ wqkv16,
    u16* __restrict__ wo16, u16* __restrict__ c116, u16* __restrict__ c216,
    u16* __restrict__ latpad, u16* __restrict__ d2pad) {
  __shared__ float xs[18][56];
  int bx = blockIdx.x;
  int t = threadIdx.x;
  if (bx < 512) {
    int lt = (bx & 15) * 16;
    int b = bx >> 4;
    for (int idx = t; idx < 18 * 55; idx += 256) {
      int rr = idx / 55, cc = idx % 55;
      int gl = (lt + rr - 1 + L_) & (L_ - 1);
      xs[rr][cc] = x[(long)(b * L_ + gl) * C_ + cc];
    }
    __syncthreads();
    for (int dp = 0; dp < 2; ++dp) {
      int d = t + dp * 256;
      float acc[16] = {};
      const float* wr = tw + (long)d * (C_ * 3);
      for (int c = 0; c < C_; ++c) {
#pragma unroll
        for (int w = 0; w < 3; ++w) {
          float wv = wr[c * 3 + w];
#pragma unroll
          for (int l = 0; l < 16; ++l) acc[l] = fmaf(xs[l + w][c], wv, acc[l]);
        }
      }
      float ang_scale = expf(-(float)(d & ~1) * 0.017988946039015984f);
#pragma unroll
      for (int l = 0; l < 16; ++l) {
        float ang = (float)(lt + l) * ang_scale;
        float pe = (d & 1) ? cosf(ang) : sinf(ang);
        float v = acc[l] + pe;
        long idx = (long)(b * L_ + lt + l) * D_ + d;
        h32[idx] = v;
        h16[idx] = f2h(v);
      }
    }
    return;
  }
  int cb = bx - 512;
  if (cb < 9216) {
    int i = cb * 256 + t;
    wqkv16[i] = f2h(qkv_w[i]);
  } else if (cb < 12288) {
    int i = (cb - 9216) * 256 + t;
    wo16[i] = f2h(out_w[i]);
  } else if (cb < 15360) {
    int i = (cb - 12288) * 256 + t;
    c116[i] = f2h(c1w[i]);
  } else if (cb < 18432) {
    int i = (cb - 15360) * 256 + t;
    c216[i] = f2h(c2w[i]);
  } else if (cb < 18560) {
    int i = (cb - 18432) * 256 + t;
    int r = i >> 9, c = i & 511;
    latpad[i] = (r < Z_) ? f2h(latw[r * 512 + c]) : (u16)0;
  } else {
    int i = (cb - 18560) * 256 + t;
    int r = i >> 9, c = i & 511;
    d2pad[i] = (r < C_) ? f2h(d2w[r * 512 + c]) : (u16)0;
  }
}

// --------- wave-per-row residual + LN (+ optional fused second LN) ---------
// 4 rows/block (one per wave), no block barriers. Row held in 8 regs/lane.
__global__ __launch_bounds__(256) void lnw_kernel(
    const float* __restrict__ a, const float* __restrict__ r,
    const float* __restrict__ gg, const float* __restrict__ be,
    float* __restrict__ ofp, u16* __restrict__ o16,
    const float* __restrict__ g2, const float* __restrict__ b2) {
  int wave = threadIdx.x >> 6, lane = threadIdx.x & 63;
  long row = (long)blockIdx.x * 4 + wave;
  long base = row * D_ + lane * 8;
  int cb = lane * 8;
  f32x4 xa = *(const f32x4*)(a + base);
  f32x4 xb = *(const f32x4*)(a + base + 4);
  if (r) {
    xa += *(const f32x4*)(r + base);
    xb += *(const f32x4*)(r + base + 4);
  }
  float x[8] = {xa.x, xa.y, xa.z, xa.w, xb.x, xb.y, xb.z, xb.w};
  float s = 0.f;
#pragma unroll
  for (int e = 0; e < 8; ++e) s += x[e];
#pragma unroll
  for (int off = 32; off > 0; off >>= 1) s += __shfl_xor(s, off, 64);
  float mean = s * (1.f / D_);
  float vv = 0.f;
#pragma unroll
  for (int e = 0; e < 8; ++e) {
    x[e] -= mean;
    vv += x[e] * x[e];
  }
#pragma unroll
  for (int off = 32; off > 0; off >>= 1) vv += __shfl_xor(vv, off, 64);
  float rstd = rsqrtf(vv * (1.f / D_) + 1e-5f);
  f32x4 ga = *(const f32x4*)(gg + cb), gb = *(const f32x4*)(gg + cb + 4);
  f32x4 ba = *(const f32x4*)(be + cb), bb = *(const f32x4*)(be + cb + 4);
  float g[8] = {ga.x, ga.y, ga.z, ga.w, gb.x, gb.y, gb.z, gb.w};
  float bi[8] = {ba.x, ba.y, ba.z, ba.w, bb.x, bb.y, bb.z, bb.w};
  float v[8];
#pragma unroll
  for (int e = 0; e < 8; ++e) v[e] = x[e] * rstd * g[e] + bi[e];
  if (ofp) {
    f32x4 oa = {v[0], v[1], v[2], v[3]}, ob = {v[4], v[5], v[6], v[7]};
    *(f32x4*)(ofp + base) = oa;
    *(f32x4*)(ofp + base + 4) = ob;
  }
  if (g2) {
    float s2 = 0.f;
#pragma unroll
    for (int e = 0; e < 8; ++e) s2 += v[e];
#pragma unroll
    for (int off = 32; off > 0; off >>= 1) s2 += __shfl_xor(s2, off, 64);
    float mean2 = s2 * (1.f / D_);
    float vv2 = 0.f;
#pragma unroll
    for (int e = 0; e < 8; ++e) {
      v[e] -= mean2;
      vv2 += v[e] * v[e];
    }
#pragma unroll
    for (int off = 32; off > 0; off >>= 1) vv2 += __shfl_xor(vv2, off, 64);
    float rstd2 = rsqrtf(vv2 * (1.f / D_) + 1e-5f);
    f32x4 g2a = *(const f32x4*)(g2 + cb), g2b = *(const f32x4*)(g2 + cb + 4);
    f32x4 b2a = *(const f32x4*)(b2 + cb), b2b = *(const f32x4*)(b2 + cb + 4);
    float gg2[8] = {g2a.x, g2a.y, g2a.z, g2a.w, g2b.x, g2b.y, g2b.z, g2b.w};
    float bb2[8] = {b2a.x, b2a.y, b2a.z, b2a.w, b2b.x, b2b.y, b2b.z, b2b.w};
#pragma unroll
    for (int e = 0; e < 8; ++e) v[e] = v[e] * rstd2 * gg2[e] + bb2[e];
  }
  if (o16) {
    u16 h[8];
#pragma unroll
    for (int e = 0; e < 8; ++e) h[e] = f2h(v[e]);
    *(s16x8*)(o16 + base) = *(s16x8*)h;
  }
}

extern "C" void kernel_launch(void* const* d_in, const int* in_sizes, int n_in,
                              void* d_out, int out_size, void* d_ws,
                              size_t ws_size, hipStream_t stream) {
  (void)in_sizes; (void)n_in; (void)out_size; (void)ws_size;
  const float* x = (const float*)d_in[0];
  const float* tok_w = (const float*)d_in[1];
  const float* qkv_w = (const float*)d_in[2];
  const float* qkv_b = (const float*)d_in[3];
  const float* sig_w = (const float*)d_in[4];
  const float* sig_b = (const float*)d_in[5];
  const float* out_w = (const float*)d_in[6];
  const float* out_b = (const float*)d_in[7];
  const float* c1w = (const float*)d_in[8];
  const float* c1b = (const float*)d_in[9];
  const float* c2w = (const float*)d_in[10];
  const float* c2b = (const float*)d_in[11];
  const float* ln1g = (const float*)d_in[12];
  const float* ln1b = (const float*)d_in[13];
  const float* ln2g = (const float*)d_in[14];
  const float* ln2b = (const float*)d_in[15];
  const float* lnfg = (const float*)d_in[16];
  const float* lnfb = (const float*)d_in[17];
  const float* latw = (const float*)d_in[18];
  const float* latb = (const float*)d_in[19];
  const float* d1w = (const float*)d_in[20];
  const float* d1b = (const float*)d_in[21];
  const float* d2w = (const float*)d_in[22];
  const float* d2b = (const float*)d_in[23];
  float* out = (float*)d_out;

  const long BLD = (long)B_ * L_ * D_;         // 4194304
  const long CHUNK = (long)B_ * H_ * L_ * L_;  // 16777216
  const long SER_OFF = (long)B_ * L_ * C_;
  const long PRI_OFF = SER_OFF + NL_ * CHUNK;
  const long Z_OFF = PRI_OFF + NL_ * CHUNK;
  const int M = B_ * L_;  // 8192
  const int DD = D_ * D_;

  char* wp = (char*)d_ws;
  auto alloc = [&](size_t bytes) {
    char* p = wp;
    wp += (bytes + 255) & ~(size_t)255;
    return p;
  };
  float* h32 = (float*)alloc(BLD * 4);
  u16* h16 = (u16*)alloc(BLD * 2);
  float* tb = (float*)alloc(BLD * 4);
  u16* qk16 = (u16*)alloc(BLD * 4);  // (M,1024); reused as y16
  u16* vt16 = (u16*)alloc(BLD * 2);  // also dec16 at tail
  u16* pv16 = (u16*)alloc(BLD * 2);
  float* coef = (float*)alloc((size_t)B_ * H_ * L_ * 4);
  float* c2f = (float*)alloc((size_t)B_ * H_ * L_ * 4);
  u16* wqkv16 = (u16*)alloc((size_t)NL_ * 3 * DD * 2);
  u16* wo16 = (u16*)alloc((size_t)NL_ * DD * 2);
  u16* c116 = (u16*)alloc((size_t)NL_ * DD * 2);
  u16* c216 = (u16*)alloc((size_t)NL_ * DD * 2);
  u16* latpad = (u16*)alloc((size_t)64 * 512 * 2);
  u16* d2pad = (u16*)alloc((size_t)64 * 512 * 2);

  // one-time prep: embed + all weight conversions, one launch (18688 blocks)
  conv_embed_kernel<<<18688, 256, 0, stream>>>(
      x, tok_w, qkv_w, out_w, c1w, c2w, latw, d2w, h32, h16, wqkv16, wo16,
      c116, c216, latpad, d2pad);

  for (int i = 0; i < NL_; ++i) {
    const long ofQK = (long)(i * 3) * DD;
    // merged sigma (first) + q,k projection (MF=2) + v^T, 9728 blocks
    qkv_kernel<<<9728, 256, 0, stream>>>(
        h16, wqkv16 + ofQK, qkv_b + (long)i * 3 * D_, qk16, vt16, h32,
        sig_w + (long)i * H_ * D_, sig_b + i * H_, coef, c2f);
    fused_attn<<<dim3(4, 256), 256, 0, stream>>>(
        qk16, vt16, qkv_b + (long)(i * 3 + 2) * D_, coef, c2f,
        out + SER_OFF + i * CHUNK, out + PRI_OFF + i * CHUNK, pv16);
    // out projection (fp32 out), MF=1: 4096 waves (4/SIMD)
    mgemm<1, 2, 1, 0, 0><<<dim3(8, 256), 128, 0, stream>>>(
        pv16, wo16 + (long)i * DD, out_b + i * D_, tb, nullptr, D_, D_, D_, D_,
        D_);
    lnw_kernel<<<M / 4, 256, 0, stream>>>(h32, tb, ln1g + i * D_,
                                          ln1b + i * D_, h32, h16, nullptr,
                                          nullptr);
    // FFN (intermediate y16 reuses qk16), MF=1
    u16* y16 = qk16;
    mgemm<1, 2, 1, 1, 1><<<dim3(8, 256), 128, 0, stream>>>(
        h16, c116 + (long)i * DD, c1b + i * DF_, nullptr, y16, D_, D_, D_, DF_,
        DF_);
    mgemm<1, 2, 1, 0, 0><<<dim3(8, 256), 128, 0, stream>>>(
        y16, c216 + (long)i * DD, c2b + i * D_, tb, nullptr, DF_, DF_, DF_, D_,
        D_);
    // trailing LN; layer 2 fuses the final LN (h32 no longer needed then)
    bool last = (i == NL_ - 1);
    lnw_kernel<<<M / 4, 256, 0, stream>>>(
        h32, tb, ln2g + i * D_, ln2b + i * D_, last ? nullptr : h32, h16,
        last ? lnfg : nullptr, last ? lnfb : nullptr);
  }
  // latent: z = LNf(h) @ latw^T + latb  (fp16 MFMA, N=16 guarded), MF=2
  mgemm<2, 2, 1, 0, 0><<<dim3(1, 128), 128, 0, stream>>>(
      h16, latpad, latb, out + Z_OFF, nullptr, D_, D_, D_, Z_, Z_);
  // d1: relu(z @ d1w^T + d1b) -> fp16 (K=16, fp32 path)
  u16* dec16 = vt16;
  gemm_kernel<2, true><<<dim3(8, 128), 256, 0, stream>>>(
      out + Z_OFF, d1w, d1b, nullptr, dec16, M, D_, Z_, Z_, Z_, D_);
  // d2: recon = dec @ d2w^T + d2b (fp16 MFMA, N=55 guarded), MF=2
  mgemm<2, 2, 1, 0, 0><<<dim3(1, 128), 128, 0, stream>>>(
      dec16, d2pad, d2b, out, nullptr, D_, D_, D_, C_, C_);
}